// Round 1
// baseline (1153.919 us; speedup 1.0000x reference)
//
#include <hip/hip_runtime.h>
#include <hip/hip_bf16.h>
#include <math.h>

#define Bn   384
#define INn  512
#define OUTn 384

typedef __bf16 bf16x8 __attribute__((ext_vector_type(8)));
typedef __bf16 bf16x4 __attribute__((ext_vector_type(4)));
typedef float  f32x4  __attribute__((ext_vector_type(4)));

// Device-global scratch (avoids any assumption about ws_size).
__device__ __bf16 g_Wbf[OUTn * INn];    // W cast to bf16, row-major [o][i]
__device__ float  g_sp [OUTn * INn];    // softplus(sigma_weight), [o][i]
__device__ float  g_d  [Bn * OUTn];     // s1 + s3 diagonal vector, [b][o]

// ---------------------------------------------------------------------------
// prep: Wbf = bf16(W); sp = softplus(sigma_weight)
// ---------------------------------------------------------------------------
__global__ __launch_bounds__(256) void prep_kernel(const float* __restrict__ W,
                                                   const float* __restrict__ sw) {
    int idx = blockIdx.x * 256 + threadIdx.x;
    if (idx < OUTn * INn) {
        g_Wbf[idx] = (__bf16)W[idx];
        float x = sw[idx];
        g_sp[idx] = (x > 20.f) ? x : log1pf(expf(x));
    }
}

// ---------------------------------------------------------------------------
// k2: mu_f[b,o] = mu[b,:]·W[o,:] + bias[o]   (fp32)
//     d[b,o]   = sum_i (sigma[b,i,i] + mu[b,i]^2) * sp[o,i] + (o==b)*sbias[o]
// one block per batch b
// ---------------------------------------------------------------------------
__global__ __launch_bounds__(128) void k2_kernel(const float* __restrict__ mu,
                                                 const float* __restrict__ sigma,
                                                 const float* __restrict__ W,
                                                 const float* __restrict__ bias,
                                                 const float* __restrict__ sbias,
                                                 float* __restrict__ out_muf) {
    int b = blockIdx.x;
    __shared__ __align__(16) float muL[INn];
    __shared__ __align__(16) float tL[INn];
    for (int i = threadIdx.x; i < INn; i += blockDim.x) {
        float m = mu[b * INn + i];
        muL[i] = m;
        tL[i] = sigma[(size_t)b * (INn * INn) + (size_t)i * (INn + 1)] + m * m;
    }
    __syncthreads();
    for (int o = threadIdx.x; o < OUTn; o += blockDim.x) {
        const float4* Wr = (const float4*)(W + (size_t)o * INn);
        const float4* Sr = (const float4*)(g_sp + (size_t)o * INn);
        const float4* Mr = (const float4*)muL;
        const float4* Tr = (const float4*)tL;
        float mf = 0.f, dd = 0.f;
        for (int i4 = 0; i4 < INn / 4; ++i4) {
            float4 w4 = Wr[i4], s4 = Sr[i4], m4 = Mr[i4], t4 = Tr[i4];
            mf += w4.x * m4.x + w4.y * m4.y + w4.z * m4.z + w4.w * m4.w;
            dd += s4.x * t4.x + s4.y * t4.y + s4.z * t4.z + s4.w * t4.w;
        }
        out_muf[b * OUTn + o] = mf + bias[o];
        g_d[b * OUTn + o] = dd + (o == b ? sbias[o] : 0.f);
    }
}

// ---------------------------------------------------------------------------
// wsw: per (b, ptile): sigma_out[b, :, p0:p0+128] = W · sigma_b · W[p-tile]^T
//      + diag(d) contribution.
// Stage A: Ut[p][i] = sum_j sigma[b,i,j] * W[p0+p, j]   (bf16 in LDS, padded)
// Stage B: out[b,o,p0+p] = sum_i W[o,i] * Ut[p][i]  (+ d[b,o] if o==p)
// block = 512 threads = 8 waves.
// MFMA 16x16x32 bf16: A/B frag = [row=lane&15][k=quad*8+j], D = [quad*4+r][lane&15]
// ---------------------------------------------------------------------------
__global__ __launch_bounds__(512) void wsw_kernel(const float* __restrict__ sigma,
                                                  float* __restrict__ outS) {
    __shared__ __bf16 Ut[128][INn + 8];   // +8 pad: stage-B ds_read_b128 -> 2-way (free)

    const int ptile = blockIdx.x;   // 0..2
    const int b     = blockIdx.y;   // 0..383
    const int tid   = threadIdx.x;
    const int wave  = tid >> 6;     // 0..7
    const int lane  = tid & 63;
    const int quad  = lane >> 4;
    const int l15   = lane & 15;
    const int p0    = ptile * 128;

    const float* sigb = sigma + (size_t)b * (INn * INn);

    // ---------------- Stage A ----------------
    for (int half = 0; half < 2; ++half) {
        const int i_base = half * 256 + wave * 32;   // wave covers 32 sigma rows
        f32x4 acc[2][8];
#pragma unroll
        for (int mi = 0; mi < 2; ++mi)
#pragma unroll
            for (int nf = 0; nf < 8; ++nf) acc[mi][nf] = (f32x4){0.f, 0.f, 0.f, 0.f};

        for (int kc = 0; kc < INn; kc += 32) {
            bf16x8 afr[2];
#pragma unroll
            for (int mi = 0; mi < 2; ++mi) {
                const float* ap = sigb + (size_t)(i_base + mi * 16 + l15) * INn + kc + quad * 8;
                float4 a0 = *(const float4*)ap;
                float4 a1 = *(const float4*)(ap + 4);
                bf16x8 t;
                t[0] = (__bf16)a0.x; t[1] = (__bf16)a0.y; t[2] = (__bf16)a0.z; t[3] = (__bf16)a0.w;
                t[4] = (__bf16)a1.x; t[5] = (__bf16)a1.y; t[6] = (__bf16)a1.z; t[7] = (__bf16)a1.w;
                afr[mi] = t;
            }
#pragma unroll
            for (int nf = 0; nf < 8; ++nf) {
                const __bf16* bp = g_Wbf + (size_t)(p0 + nf * 16 + l15) * INn + kc + quad * 8;
                bf16x8 bfr = *(const bf16x8*)bp;
                acc[0][nf] = __builtin_amdgcn_mfma_f32_16x16x32_bf16(afr[0], bfr, acc[0][nf], 0, 0, 0);
                acc[1][nf] = __builtin_amdgcn_mfma_f32_16x16x32_bf16(afr[1], bfr, acc[1][nf], 0, 0, 0);
            }
        }
        // write transposed to LDS: lane holds D[i_local = quad*4+r][p_local = l15]
#pragma unroll
        for (int mi = 0; mi < 2; ++mi) {
            int ib = i_base + mi * 16 + quad * 4;
#pragma unroll
            for (int nf = 0; nf < 8; ++nf) {
                int p = nf * 16 + l15;
                bf16x4 v;
                v[0] = (__bf16)acc[mi][nf][0];
                v[1] = (__bf16)acc[mi][nf][1];
                v[2] = (__bf16)acc[mi][nf][2];
                v[3] = (__bf16)acc[mi][nf][3];
                *(bf16x4*)&Ut[p][ib] = v;
            }
        }
    }
    __syncthreads();

    // ---------------- Stage B ----------------
    {
        const int o_base = wave * 48;   // 8 waves x 48 rows = 384
        f32x4 acc[3][8];
#pragma unroll
        for (int mi = 0; mi < 3; ++mi)
#pragma unroll
            for (int nf = 0; nf < 8; ++nf) acc[mi][nf] = (f32x4){0.f, 0.f, 0.f, 0.f};

        for (int kc = 0; kc < INn; kc += 32) {
            bf16x8 afr[3];
#pragma unroll
            for (int mi = 0; mi < 3; ++mi) {
                const __bf16* ap = g_Wbf + (size_t)(o_base + mi * 16 + l15) * INn + kc + quad * 8;
                afr[mi] = *(const bf16x8*)ap;
            }
#pragma unroll
            for (int nf = 0; nf < 8; ++nf) {
                bf16x8 bfr = *(const bf16x8*)&Ut[nf * 16 + l15][kc + quad * 8];
                acc[0][nf] = __builtin_amdgcn_mfma_f32_16x16x32_bf16(afr[0], bfr, acc[0][nf], 0, 0, 0);
                acc[1][nf] = __builtin_amdgcn_mfma_f32_16x16x32_bf16(afr[1], bfr, acc[1][nf], 0, 0, 0);
                acc[2][nf] = __builtin_amdgcn_mfma_f32_16x16x32_bf16(afr[2], bfr, acc[2][nf], 0, 0, 0);
            }
        }
        // epilogue: add diagonal, store fp32
        float* outb = outS + (size_t)b * (OUTn * OUTn);
#pragma unroll
        for (int mi = 0; mi < 3; ++mi) {
            int o_r = o_base + mi * 16 + quad * 4;
#pragma unroll
            for (int nf = 0; nf < 8; ++nf) {
                int p = p0 + nf * 16 + l15;
#pragma unroll
                for (int r = 0; r < 4; ++r) {
                    int o = o_r + r;
                    float v = acc[mi][nf][r];
                    if (o == p) v += g_d[b * OUTn + o];
                    outb[(size_t)o * OUTn + p] = v;
                }
            }
        }
    }
}

// ---------------------------------------------------------------------------
extern "C" void kernel_launch(void* const* d_in, const int* in_sizes, int n_in,
                              void* d_out, int out_size, void* d_ws, size_t ws_size,
                              hipStream_t stream) {
    const float* mu    = (const float*)d_in[0];
    const float* sigma = (const float*)d_in[1];
    const float* W     = (const float*)d_in[2];
    const float* bias  = (const float*)d_in[3];
    const float* sw    = (const float*)d_in[4];
    const float* sbias = (const float*)d_in[5];

    float* out     = (float*)d_out;
    float* out_muf = out;                  // [384, 384]
    float* out_sig = out + Bn * OUTn;      // [384, 384, 384]

    prep_kernel<<<(OUTn * INn + 255) / 256, 256, 0, stream>>>(W, sw);
    k2_kernel<<<Bn, 128, 0, stream>>>(mu, sigma, W, bias, sbias, out_muf);
    wsw_kernel<<<dim3(3, Bn), 512, 0, stream>>>(sigma, out_sig);
}

// Round 2
// 1049.709 us; speedup vs baseline: 1.0993x; 1.0993x over previous
//
#include <hip/hip_runtime.h>
#include <hip/hip_bf16.h>
#include <math.h>

#define Bn   384
#define INn  512
#define OUTn 384

typedef __bf16 bf16x8 __attribute__((ext_vector_type(8)));
typedef __bf16 bf16x4 __attribute__((ext_vector_type(4)));
typedef float  f32x4  __attribute__((ext_vector_type(4)));

// Device-global scratch (avoids any assumption about ws_size).
__device__ __bf16 g_Wbf[OUTn * INn];    // W cast to bf16, row-major [o][i]
__device__ float  g_sp [OUTn * INn];    // softplus(sigma_weight), [o][i]
__device__ float  g_d  [Bn * OUTn];     // s1 + s3 diagonal vector, [b][o]

// ---------------------------------------------------------------------------
// prep: Wbf = bf16(W); sp = softplus(sigma_weight)
// ---------------------------------------------------------------------------
__global__ __launch_bounds__(256) void prep_kernel(const float* __restrict__ W,
                                                   const float* __restrict__ sw) {
    int idx = blockIdx.x * 256 + threadIdx.x;
    if (idx < OUTn * INn) {
        g_Wbf[idx] = (__bf16)W[idx];
        float x = sw[idx];
        g_sp[idx] = (x > 20.f) ? x : log1pf(expf(x));
    }
}

// ---------------------------------------------------------------------------
// k2: mu_f[b,o] = mu[b,:]·W[o,:] + bias[o]   (fp32)
//     d[b,o]   = sum_i (sigma[b,i,i] + mu[b,i]^2) * sp[o,i] + (o==b)*sbias[o]
// grid (b, oq): block = 256 threads = 4 waves; each wave does 24 o's with
// coalesced full-row loads + butterfly reduction.
// ---------------------------------------------------------------------------
__global__ __launch_bounds__(256) void k2_kernel(const float* __restrict__ mu,
                                                 const float* __restrict__ sigma,
                                                 const float* __restrict__ W,
                                                 const float* __restrict__ bias,
                                                 const float* __restrict__ sbias,
                                                 float* __restrict__ out_muf) {
    const int b  = blockIdx.x;
    const int oq = blockIdx.y;   // 0..3
    __shared__ __align__(16) float muL[INn];
    __shared__ __align__(16) float tL[INn];
    const int tid = threadIdx.x;
    for (int i = tid; i < INn; i += 256) {
        float m = mu[b * INn + i];
        muL[i] = m;
        tL[i] = sigma[(size_t)b * (INn * INn) + (size_t)i * (INn + 1)] + m * m;
    }
    __syncthreads();
    const int wave = tid >> 6, lane = tid & 63;
    const float4* Mr = (const float4*)muL;
    const float4* Tr = (const float4*)tL;
    float4 m0 = Mr[lane * 2], m1 = Mr[lane * 2 + 1];
    float4 t0 = Tr[lane * 2], t1 = Tr[lane * 2 + 1];
#pragma unroll 4
    for (int ow = 0; ow < 24; ++ow) {
        const int o = oq * 96 + wave * 24 + ow;
        const float4* Wr = (const float4*)(W + (size_t)o * INn);
        const float4* Sr = (const float4*)(g_sp + (size_t)o * INn);
        float4 w0 = Wr[lane * 2], w1 = Wr[lane * 2 + 1];
        float4 s0 = Sr[lane * 2], s1 = Sr[lane * 2 + 1];
        float mf = w0.x * m0.x + w0.y * m0.y + w0.z * m0.z + w0.w * m0.w
                 + w1.x * m1.x + w1.y * m1.y + w1.z * m1.z + w1.w * m1.w;
        float dd = s0.x * t0.x + s0.y * t0.y + s0.z * t0.z + s0.w * t0.w
                 + s1.x * t1.x + s1.y * t1.y + s1.z * t1.z + s1.w * t1.w;
#pragma unroll
        for (int off = 32; off; off >>= 1) {
            mf += __shfl_xor(mf, off, 64);
            dd += __shfl_xor(dd, off, 64);
        }
        if (lane == 0) {
            out_muf[b * OUTn + o] = mf + bias[o];
            g_d[b * OUTn + o] = dd + (o == b ? sbias[o] : 0.f);
        }
    }
}

// ---------------------------------------------------------------------------
// wsw: per (b, ptile of 64): sigma_out[b, :, p0:p0+64] = W · sigma_b · Wt-tile
//      + diag contribution.
// Stage A: Ut[p][i] = sum_j sigma[b,i,j] * W[p0+p, j]   (bf16 in LDS, padded)
// Stage B: out[b,o,p0+p] = sum_i W[o,i] * Ut[p][i]  (+ d[b,o] if o==p)
// block = 512 threads = 8 waves; LDS 64x520x2 = 66,560 B -> 2 blocks/CU.
// __launch_bounds__(512,4): 4 waves/EU = 16 waves/CU -> VGPR capped at 128.
// MFMA 16x16x32 bf16: A/B frag = [row=lane&15][k=quad*8+j], D = [quad*4+r][lane&15]
// ---------------------------------------------------------------------------
__global__ __launch_bounds__(512, 4) void wsw_kernel(const float* __restrict__ sigma,
                                                     float* __restrict__ outS) {
    __shared__ __bf16 Ut[64][INn + 8];   // stride 520*2B = 1040B (16B-aligned)

    const int ptile = blockIdx.x;   // 0..5
    const int b     = blockIdx.y;   // 0..383
    const int tid   = threadIdx.x;
    const int wave  = tid >> 6;     // 0..7
    const int lane  = tid & 63;
    const int quad  = lane >> 4;
    const int l15   = lane & 15;
    const int p0    = ptile * 64;

    const float* sigb = sigma + (size_t)b * (INn * INn);

    // ---------------- Stage A ----------------
    {
        const int i_base = wave * 64;   // wave covers 64 sigma rows
        f32x4 acc[4][4];
#pragma unroll
        for (int mi = 0; mi < 4; ++mi)
#pragma unroll
            for (int nf = 0; nf < 4; ++nf) acc[mi][nf] = (f32x4){0.f, 0.f, 0.f, 0.f};

        for (int kc = 0; kc < INn; kc += 32) {
            bf16x8 afr[4];
#pragma unroll
            for (int mi = 0; mi < 4; ++mi) {
                const float* ap = sigb + (size_t)(i_base + mi * 16 + l15) * INn + kc + quad * 8;
                float4 a0 = *(const float4*)ap;
                float4 a1 = *(const float4*)(ap + 4);
                bf16x8 t;
                t[0] = (__bf16)a0.x; t[1] = (__bf16)a0.y; t[2] = (__bf16)a0.z; t[3] = (__bf16)a0.w;
                t[4] = (__bf16)a1.x; t[5] = (__bf16)a1.y; t[6] = (__bf16)a1.z; t[7] = (__bf16)a1.w;
                afr[mi] = t;
            }
#pragma unroll
            for (int nf = 0; nf < 4; ++nf) {
                const __bf16* bp = g_Wbf + (size_t)(p0 + nf * 16 + l15) * INn + kc + quad * 8;
                bf16x8 bfr = *(const bf16x8*)bp;
#pragma unroll
                for (int mi = 0; mi < 4; ++mi)
                    acc[mi][nf] = __builtin_amdgcn_mfma_f32_16x16x32_bf16(afr[mi], bfr, acc[mi][nf], 0, 0, 0);
            }
        }
        // write transposed to LDS: lane holds D[i_local = quad*4+r][p_local = l15]
#pragma unroll
        for (int mi = 0; mi < 4; ++mi) {
            int ib = i_base + mi * 16 + quad * 4;
#pragma unroll
            for (int nf = 0; nf < 4; ++nf) {
                int p = nf * 16 + l15;
                bf16x4 v;
                v[0] = (__bf16)acc[mi][nf][0];
                v[1] = (__bf16)acc[mi][nf][1];
                v[2] = (__bf16)acc[mi][nf][2];
                v[3] = (__bf16)acc[mi][nf][3];
                *(bf16x4*)&Ut[p][ib] = v;
            }
        }
    }
    __syncthreads();

    // ---------------- Stage B ----------------
    {
        const int o_base = wave * 48;   // 8 waves x 48 rows = 384
        f32x4 acc[3][4];
#pragma unroll
        for (int mi = 0; mi < 3; ++mi)
#pragma unroll
            for (int nf = 0; nf < 4; ++nf) acc[mi][nf] = (f32x4){0.f, 0.f, 0.f, 0.f};

        for (int kc = 0; kc < INn; kc += 32) {
            bf16x8 afr[3];
#pragma unroll
            for (int mi = 0; mi < 3; ++mi) {
                const __bf16* ap = g_Wbf + (size_t)(o_base + mi * 16 + l15) * INn + kc + quad * 8;
                afr[mi] = *(const bf16x8*)ap;
            }
#pragma unroll
            for (int nf = 0; nf < 4; ++nf) {
                bf16x8 bfr = *(const bf16x8*)&Ut[nf * 16 + l15][kc + quad * 8];
#pragma unroll
                for (int mi = 0; mi < 3; ++mi)
                    acc[mi][nf] = __builtin_amdgcn_mfma_f32_16x16x32_bf16(afr[mi], bfr, acc[mi][nf], 0, 0, 0);
            }
        }
        // epilogue: add diagonal, store fp32
        float* outb = outS + (size_t)b * (OUTn * OUTn);
#pragma unroll
        for (int mi = 0; mi < 3; ++mi) {
            int o_r = o_base + mi * 16 + quad * 4;
#pragma unroll
            for (int nf = 0; nf < 4; ++nf) {
                int p = p0 + nf * 16 + l15;
#pragma unroll
                for (int r = 0; r < 4; ++r) {
                    int o = o_r + r;
                    float v = acc[mi][nf][r];
                    if (o == p) v += g_d[b * OUTn + o];
                    outb[(size_t)o * OUTn + p] = v;
                }
            }
        }
    }
}

// ---------------------------------------------------------------------------
extern "C" void kernel_launch(void* const* d_in, const int* in_sizes, int n_in,
                              void* d_out, int out_size, void* d_ws, size_t ws_size,
                              hipStream_t stream) {
    const float* mu    = (const float*)d_in[0];
    const float* sigma = (const float*)d_in[1];
    const float* W     = (const float*)d_in[2];
    const float* bias  = (const float*)d_in[3];
    const float* sw    = (const float*)d_in[4];
    const float* sbias = (const float*)d_in[5];

    float* out     = (float*)d_out;
    float* out_muf = out;                  // [384, 384]
    float* out_sig = out + Bn * OUTn;      // [384, 384, 384]

    prep_kernel<<<(OUTn * INn + 255) / 256, 256, 0, stream>>>(W, sw);
    k2_kernel<<<dim3(Bn, 4), 256, 0, stream>>>(mu, sigma, W, bias, sbias, out_muf);
    wsw_kernel<<<dim3(6, Bn), 512, 0, stream>>>(sigma, out_sig);
}